// Round 4
// baseline (257.414 us; speedup 1.0000x reference)
//
#include <hip/hip_runtime.h>
#include <hip/hip_bf16.h>

// ---------------------------------------------------------------------------
// Attention: B=2,N=2048,C=768,H=12,HD=64.  Inputs fp32, OUTPUT fp32 (per
// harness contract: d_out = reference output dtype = float32).
//   K1: convert x, W_qkv, W_proj fp32 -> f16 in ws
//   K2: qkv[token][2304] = x @ Wqkv^T + b   (plain GEMM)
//   K3: flash attention per (bh, 64-query tile); V transposed in LDS;
//       P round-trip through LDS with full __syncthreads barriers
//   K4: out = ao @ Wproj^T + b  -> float d_out
// ---------------------------------------------------------------------------

typedef _Float16 half8 __attribute__((ext_vector_type(8)));
typedef _Float16 half4_t __attribute__((ext_vector_type(4)));
typedef float floatx4 __attribute__((ext_vector_type(4)));

#define LDA 72                      // LDS row stride in halves (64+8 pad)
#define SCALE_LOG2E 0.1803368801111204f   // (1/8) * log2(e)

// ws layout in _Float16 elements
constexpr int XH_OFF    = 0;                          // x as f16: 4096*768
constexpr int WQKV_OFF  = XH_OFF + 4096 * 768;        // 3145728
constexpr int WPROJ_OFF = WQKV_OFF + 2304 * 768;      // 4915200
constexpr int QKV_OFF   = WPROJ_OFF + 768 * 768;      // 5505024
// qkv: 4096*2304 -> total 14942208 halves (~29.9 MB). aoh reuses XH region.

// ---------------------------------------------------------------- K1: convert
__global__ __launch_bounds__(256) void cvt_all(const float* __restrict__ x,
                                               const float* __restrict__ wqkv,
                                               const float* __restrict__ wproj,
                                               _Float16* __restrict__ ws) {
  constexpr int n1 = 4096 * 768 / 4;   // x vec4 count
  constexpr int n2 = 2304 * 768 / 4;   // wqkv vec4 count
  int i = blockIdx.x * 256 + threadIdx.x;
  const float* src; _Float16* dst; int j;
  if (i < n1)           { src = x;     dst = ws + XH_OFF;    j = i; }
  else if (i < n1 + n2) { src = wqkv;  dst = ws + WQKV_OFF;  j = i - n1; }
  else                  { src = wproj; dst = ws + WPROJ_OFF; j = i - n1 - n2; }
  floatx4 f = *(const floatx4*)(src + 4 * j);
  half4_t h;
  h[0] = (_Float16)f[0]; h[1] = (_Float16)f[1];
  h[2] = (_Float16)f[2]; h[3] = (_Float16)f[3];
  *(half4_t*)(dst + 4 * j) = h;
}

// ------------------------------------------- K2: qkv GEMM (M=4096,N=2304,K=768)
__global__ __launch_bounds__(256) void qkv_gemm(const _Float16* __restrict__ xh,
                                                const _Float16* __restrict__ wh,
                                                const float* __restrict__ bias,
                                                _Float16* __restrict__ qkvh) {
  __shared__ __align__(16) _Float16 sA[128 * LDA];
  __shared__ __align__(16) _Float16 sB[128 * LDA];
  const int tid = threadIdx.x;
  const int nblk = blockIdx.x % 18, mblk = blockIdx.x / 18;
  const int lane = tid & 63, w = tid >> 6;
  const int lane15 = lane & 15, quad = lane >> 4;
  const int wm = w >> 1, wn = w & 1;
  const int chunk = tid & 7, rbase = tid >> 3;   // staging: 8 chunks x 32 rows

  const int Abase = mblk * 128 * 768;
  const int Bbase = nblk * 128 * 768;

  floatx4 acc[4][4];
#pragma unroll
  for (int mt = 0; mt < 4; ++mt)
#pragma unroll
    for (int nt = 0; nt < 4; ++nt) acc[mt][nt] = (floatx4){0.f, 0.f, 0.f, 0.f};

  for (int kt = 0; kt < 12; ++kt) {
    half8 ta[4], tb[4];
#pragma unroll
    for (int i = 0; i < 4; ++i) {
      int row = rbase + 32 * i;
      ta[i] = *(const half8*)(xh + Abase + row * 768 + kt * 64 + chunk * 8);
      tb[i] = *(const half8*)(wh + Bbase + row * 768 + kt * 64 + chunk * 8);
    }
    if (kt) __syncthreads();
#pragma unroll
    for (int i = 0; i < 4; ++i) {
      int row = rbase + 32 * i;
      *(half8*)(sA + row * LDA + chunk * 8) = ta[i];
      *(half8*)(sB + row * LDA + chunk * 8) = tb[i];
    }
    __syncthreads();
#pragma unroll
    for (int ks = 0; ks < 2; ++ks) {
      half8 af[4], bf[4];
#pragma unroll
      for (int mt = 0; mt < 4; ++mt)
        af[mt] = *(const half8*)(sA + (wm * 64 + mt * 16 + lane15) * LDA + ks * 32 + quad * 8);
#pragma unroll
      for (int nt = 0; nt < 4; ++nt)
        bf[nt] = *(const half8*)(sB + (wn * 64 + nt * 16 + lane15) * LDA + ks * 32 + quad * 8);
#pragma unroll
      for (int mt = 0; mt < 4; ++mt)
#pragma unroll
        for (int nt = 0; nt < 4; ++nt)
          acc[mt][nt] = __builtin_amdgcn_mfma_f32_16x16x32_f16(af[mt], bf[nt], acc[mt][nt], 0, 0, 0);
    }
  }

  // plain row-major epilogue: qkv[token][col], col in [0,2304)
  const int mbase = mblk * 128 + wm * 64;
  const int nbase = nblk * 128 + wn * 64;
#pragma unroll
  for (int nt = 0; nt < 4; ++nt) {
    int col = nbase + nt * 16 + lane15;
    float bv = bias[col];
#pragma unroll
    for (int mt = 0; mt < 4; ++mt)
#pragma unroll
      for (int r = 0; r < 4; ++r) {
        int token = mbase + mt * 16 + quad * 4 + r;    // C/D: row=quad*4+r, col=lane15
        qkvh[token * 2304 + col] = (_Float16)(acc[mt][nt][r] + bv);
      }
  }
}

// ---------------------------------------------------------------- K3: attention
__global__ __launch_bounds__(256) void attn_fused(const _Float16* __restrict__ qkvh,
                                                  _Float16* __restrict__ aoh) {
  __shared__ __align__(16) _Float16 sK[64 * LDA];   // [key-in-tile][d]
  __shared__ __align__(16) _Float16 sV[64 * LDA];   // [d][key-in-tile]  (transposed)
  __shared__ __align__(16) _Float16 sP[4 * 16 * LDA];
  const int tid = threadIdx.x;
  const int bh = blockIdx.x >> 5, qt = blockIdx.x & 31;
  const int b = bh / 12, h = bh % 12;
  const int lane = tid & 63, w = tid >> 6;
  const int lane15 = lane & 15, quad = lane >> 4;
  const int chunk = tid & 7, rbase = tid >> 3;
  _Float16* sPw = sP + w * 16 * LDA;

  // base of this (b,h)'s q block inside qkv[token][2304]
  const int qbase = b * 2048 * 2304 + h * 64;

  // Q fragments (A-layout): m = query-in-wave-tile = lane15, k = d
  const int qrow = qt * 64 + w * 16 + lane15;
  half8 qa0 = *(const half8*)(qkvh + qbase + qrow * 2304 + quad * 8);
  half8 qa1 = *(const half8*)(qkvh + qbase + qrow * 2304 + 32 + quad * 8);

  floatx4 O[4];
#pragma unroll
  for (int dt = 0; dt < 4; ++dt) O[dt] = (floatx4){0.f, 0.f, 0.f, 0.f};
  float mrow[4], lrow[4];
#pragma unroll
  for (int r = 0; r < 4; ++r) { mrow[r] = -3.0e38f; lrow[r] = 0.f; }

  for (int kt = 0; kt < 32; ++kt) {
    // stage K rows [key][d] and V rows (to be transposed)
    half8 tk[2], tv[2];
#pragma unroll
    for (int i = 0; i < 2; ++i) {
      int key = kt * 64 + rbase + 32 * i;
      tk[i] = *(const half8*)(qkvh + qbase + 768 + key * 2304 + chunk * 8);
      tv[i] = *(const half8*)(qkvh + qbase + 1536 + key * 2304 + chunk * 8);
    }
    __syncthreads();   // everyone done with sK/sV/sP of previous tile
#pragma unroll
    for (int i = 0; i < 2; ++i) {
      int row = rbase + 32 * i;
      *(half8*)(sK + row * LDA + chunk * 8) = tk[i];
#pragma unroll
      for (int e = 0; e < 8; ++e)                 // LDS transpose: sV[d][key]
        sV[(chunk * 8 + e) * LDA + row] = tv[i][e];
    }
    __syncthreads();   // staging visible

    // scores S[query][key]: A=Q (m=query,k=d), B=K (k=d,n=key)
    floatx4 s[4];
#pragma unroll
    for (int nt = 0; nt < 4; ++nt) {
      half8 kb0 = *(const half8*)(sK + (nt * 16 + lane15) * LDA + quad * 8);
      half8 kb1 = *(const half8*)(sK + (nt * 16 + lane15) * LDA + 32 + quad * 8);
      floatx4 a = (floatx4){0.f, 0.f, 0.f, 0.f};
      a = __builtin_amdgcn_mfma_f32_16x16x32_f16(qa0, kb0, a, 0, 0, 0);
      a = __builtin_amdgcn_mfma_f32_16x16x32_f16(qa1, kb1, a, 0, 0, 0);
#pragma unroll
      for (int r = 0; r < 4; ++r) a[r] *= SCALE_LOG2E;   // into log2 domain
      s[nt] = a;
    }

    // online softmax; row = query = quad*4+r, cols across the quad's 16 lanes
    float cmax[4];
#pragma unroll
    for (int r = 0; r < 4; ++r)
      cmax[r] = fmaxf(fmaxf(s[0][r], s[1][r]), fmaxf(s[2][r], s[3][r]));
#pragma unroll
    for (int off = 1; off <= 8; off <<= 1)
#pragma unroll
      for (int r = 0; r < 4; ++r) cmax[r] = fmaxf(cmax[r], __shfl_xor(cmax[r], off, 64));
    float mnew[4], alpha[4], rsum[4];
#pragma unroll
    for (int r = 0; r < 4; ++r) {
      mnew[r] = fmaxf(mrow[r], cmax[r]);
      alpha[r] = exp2f(mrow[r] - mnew[r]);
      rsum[r] = 0.f;
    }
#pragma unroll
    for (int nt = 0; nt < 4; ++nt)
#pragma unroll
      for (int r = 0; r < 4; ++r) {
        float p = exp2f(s[nt][r] - mnew[r]);
        s[nt][r] = p;
        rsum[r] += p;
      }
#pragma unroll
    for (int off = 1; off <= 8; off <<= 1)
#pragma unroll
      for (int r = 0; r < 4; ++r) rsum[r] += __shfl_xor(rsum[r], off, 64);
#pragma unroll
    for (int r = 0; r < 4; ++r) {
      lrow[r] = lrow[r] * alpha[r] + rsum[r];
      mrow[r] = mnew[r];
    }
#pragma unroll
    for (int dt = 0; dt < 4; ++dt)
#pragma unroll
      for (int r = 0; r < 4; ++r) O[dt][r] *= alpha[r];

    // P: C-layout -> LDS row-major [query][key], then full barrier
#pragma unroll
    for (int nt = 0; nt < 4; ++nt)
#pragma unroll
      for (int r = 0; r < 4; ++r)
        sPw[(quad * 4 + r) * LDA + nt * 16 + lane15] = (_Float16)s[nt][r];
    __syncthreads();   // all P (and earlier) LDS writes drained

    // PV: A=P (m=query,k=key), B=V (k=key,n=d)
#pragma unroll
    for (int kk = 0; kk < 2; ++kk) {
      half8 pa = *(const half8*)(sPw + lane15 * LDA + kk * 32 + quad * 8);
#pragma unroll
      for (int dt = 0; dt < 4; ++dt) {
        half8 vb = *(const half8*)(sV + (dt * 16 + lane15) * LDA + kk * 32 + quad * 8);
        O[dt] = __builtin_amdgcn_mfma_f32_16x16x32_f16(pa, vb, O[dt], 0, 0, 0);
      }
    }
    // top-of-loop barrier protects sK/sV/sP before next tile's writes
  }

  float inv[4];
#pragma unroll
  for (int r = 0; r < 4; ++r) inv[r] = 1.0f / lrow[r];
#pragma unroll
  for (int dt = 0; dt < 4; ++dt)
#pragma unroll
    for (int r = 0; r < 4; ++r) {
      int tok = qt * 64 + w * 16 + quad * 4 + r;
      aoh[(b * 2048 + tok) * 768 + h * 64 + dt * 16 + lane15] = (_Float16)(O[dt][r] * inv[r]);
    }
}

// ------------------------------------------- K4: proj GEMM (M=4096,N=768,K=768)
__global__ __launch_bounds__(256) void proj_gemm(const _Float16* __restrict__ ah,
                                                 const _Float16* __restrict__ wh,
                                                 const float* __restrict__ bias,
                                                 float* __restrict__ out) {
  __shared__ __align__(16) _Float16 sA[128 * LDA];
  __shared__ __align__(16) _Float16 sB[128 * LDA];
  const int tid = threadIdx.x;
  const int nblk = blockIdx.x % 6, mblk = blockIdx.x / 6;
  const int lane = tid & 63, w = tid >> 6;
  const int lane15 = lane & 15, quad = lane >> 4;
  const int wm = w >> 1, wn = w & 1;
  const int chunk = tid & 7, rbase = tid >> 3;

  const int Abase = mblk * 128 * 768;
  const int Bbase = nblk * 128 * 768;

  floatx4 acc[4][4];
#pragma unroll
  for (int mt = 0; mt < 4; ++mt)
#pragma unroll
    for (int nt = 0; nt < 4; ++nt) acc[mt][nt] = (floatx4){0.f, 0.f, 0.f, 0.f};

  for (int kt = 0; kt < 12; ++kt) {
    half8 ta[4], tb[4];
#pragma unroll
    for (int i = 0; i < 4; ++i) {
      int row = rbase + 32 * i;
      ta[i] = *(const half8*)(ah + Abase + row * 768 + kt * 64 + chunk * 8);
      tb[i] = *(const half8*)(wh + Bbase + row * 768 + kt * 64 + chunk * 8);
    }
    if (kt) __syncthreads();
#pragma unroll
    for (int i = 0; i < 4; ++i) {
      int row = rbase + 32 * i;
      *(half8*)(sA + row * LDA + chunk * 8) = ta[i];
      *(half8*)(sB + row * LDA + chunk * 8) = tb[i];
    }
    __syncthreads();
#pragma unroll
    for (int ks = 0; ks < 2; ++ks) {
      half8 af[4], bf[4];
#pragma unroll
      for (int mt = 0; mt < 4; ++mt)
        af[mt] = *(const half8*)(sA + (wm * 64 + mt * 16 + lane15) * LDA + ks * 32 + quad * 8);
#pragma unroll
      for (int nt = 0; nt < 4; ++nt)
        bf[nt] = *(const half8*)(sB + (wn * 64 + nt * 16 + lane15) * LDA + ks * 32 + quad * 8);
#pragma unroll
      for (int mt = 0; mt < 4; ++mt)
#pragma unroll
        for (int nt = 0; nt < 4; ++nt)
          acc[mt][nt] = __builtin_amdgcn_mfma_f32_16x16x32_f16(af[mt], bf[nt], acc[mt][nt], 0, 0, 0);
    }
  }

  const int mbase = mblk * 128 + wm * 64;
  const int nbase = nblk * 128 + wn * 64;
#pragma unroll
  for (int nt = 0; nt < 4; ++nt) {
    int col = nbase + nt * 16 + lane15;
    float bv = bias[col];
#pragma unroll
    for (int mt = 0; mt < 4; ++mt)
#pragma unroll
      for (int r = 0; r < 4; ++r) {
        int token = mbase + mt * 16 + quad * 4 + r;
        out[token * 768 + col] = acc[mt][nt][r] + bv;
      }
  }
}

// ---------------------------------------------------------------- launch
extern "C" void kernel_launch(void* const* d_in, const int* in_sizes, int n_in,
                              void* d_out, int out_size, void* d_ws, size_t ws_size,
                              hipStream_t stream) {
  const float* x     = (const float*)d_in[0];
  // d_in[1] = xpos (unused: rope is None)
  const float* wqkv  = (const float*)d_in[2];
  const float* bqkv  = (const float*)d_in[3];
  const float* wproj = (const float*)d_in[4];
  const float* bproj = (const float*)d_in[5];
  float* out = (float*)d_out;

  _Float16* ws = (_Float16*)d_ws;
  _Float16* xh     = ws + XH_OFF;
  _Float16* wqkvh  = ws + WQKV_OFF;
  _Float16* wprojh = ws + WPROJ_OFF;
  _Float16* qkvh   = ws + QKV_OFF;
  _Float16* aoh    = xh;   // x dead after qkv_gemm

  constexpr int total_v4 = (4096 * 768 + 2304 * 768 + 768 * 768) / 4;  // 1376256
  cvt_all<<<total_v4 / 256, 256, 0, stream>>>(x, wqkv, wproj, ws);
  qkv_gemm<<<32 * 18, 256, 0, stream>>>(xh, wqkvh, bqkv, qkvh);
  attn_fused<<<24 * 32, 256, 0, stream>>>(qkvh, aoh);
  proj_gemm<<<32 * 6, 256, 0, stream>>>(aoh, wprojh, bproj, out);
}